// Round 6
// baseline (180.605 us; speedup 1.0000x reference)
//
#include <hip/hip_runtime.h>

// NCC2D fused: 5 box-sums (9x9, zero-pad) + cc + global mean.
// R6 REDESIGN (lesson from R1-R5: kernel is latency-bound; the 2-col halo
// design paid 5 global loads/output and needed a 90-float ring that either
// spilled (R1, cheap but latency-bound) or ate occupancy (R5, VGPR=116 ->
// 4 waves/SIMD, SLOWER). New structure:
//   * 128 threads own 4 contiguous cols each (float4) -> full 512-col width.
//   * Vertical 9-row running sums V in 20 NAMED scalars; the outgoing row is
//     RE-READ from global (L2-resident, read 9 steps earlier) -> no ring.
//   * Horizontal 9-sums via LDS exchange: write V (5xb128), sync, read
//     12-col window (15xb128, conflict-free), sliding sum -> 4 outputs.
//   * 1.5 glb loads/output (vs 5), ~5 LDS ops/output, state ~70-90 VGPR.
//   * Grid 32x64 = 2048 blocks = exactly 8 blocks/CU, 16 waves/CU resident
//     (LDS 10.4KB x 8 = 83KB, launch_bounds(128,4) caps VGPR at 128).
// d_ws: 2048 block partials (float). Kernel 2 reduces in double -> -mean.

#define BATCH   32
#define IMH     512
#define IMW     512
#define SH      8            // output rows per block
#define NSTRIP  64           // 512/8, exact, no tail
#define NPART   (BATCH * NSTRIP)   // 2048
#define VROW    520          // 4 left pad + 512 + 4 right pad

// load one row's 4 owned cols from both images (zeros if row OOB)
#define LOADROW(RI, A0,A1,A2,A3, B0,B1,B2,B3) do {                         \
    const int ri_ = (RI);                                                  \
    if ((unsigned)ri_ < (unsigned)IMH) {                                   \
        const float4 iv_ = *(const float4*)(Ib + (size_t)ri_ * IMW + c0);  \
        const float4 jv_ = *(const float4*)(Jb + (size_t)ri_ * IMW + c0);  \
        A0 = iv_.x; A1 = iv_.y; A2 = iv_.z; A3 = iv_.w;                    \
        B0 = jv_.x; B1 = jv_.y; B2 = jv_.z; B3 = jv_.w;                    \
    } else {                                                               \
        A0 = A1 = A2 = A3 = 0.f; B0 = B1 = B2 = B3 = 0.f;                  \
    }                                                                      \
} while (0)

// vertical running-sum update for column M: add new (A,B), subtract old (OA,OB)
#define VUPD(M, A, B, OA, OB) do {                                         \
    VI##M  += (A) - (OA);                                                  \
    VJ##M  += (B) - (OB);                                                  \
    VII##M += (A)*(A) - (OA)*(OA);                                         \
    VJJ##M += (B)*(B) - (OB)*(OB);                                         \
    VIJ##M += (A)*(B) - (OA)*(OB);                                         \
} while (0)

// horizontal 9-window sums for 4 outputs from Vbuf row QI.
// window cols 4u-4..4u+7 = idx c0..c0+11 (idx = col+4).
#define HSUM(QI, H0, H1, H2, H3) do {                                      \
    const float4 wa_ = *(const float4*)&Vbuf[QI][c0];                      \
    const float4 wb_ = *(const float4*)&Vbuf[QI][c0 + 4];                  \
    const float4 wc_ = *(const float4*)&Vbuf[QI][c0 + 8];                  \
    const float s_ = ((wa_.x + wa_.y) + (wa_.z + wa_.w))                   \
                   + ((wb_.x + wb_.y) + (wb_.z + wb_.w)) + wc_.x;          \
    H0 = s_;                                                               \
    H1 = H0 + wc_.y - wa_.x;                                               \
    H2 = H1 + wc_.z - wa_.y;                                               \
    H3 = H2 + wc_.w - wa_.z;                                               \
} while (0)

#define CC1(AI, AJ, S2, S3, S4) do {                                       \
    const float cross = (S4) - (AI)*(AJ)*inv81;                            \
    const float ivv   = (S2) - (AI)*(AI)*inv81;                            \
    const float jvv   = (S3) - (AJ)*(AJ)*inv81;                            \
    acc += cross * cross * __builtin_amdgcn_rcpf(ivv * jvv + 1e-5f);       \
} while (0)

// one input row step. K compile-time; SUB: subtract outgoing row (K>=9);
// EMIT: output row r0+K-8 (K>=8). All threads uniform -> barriers safe.
#define STEP(K, SUB, EMIT) do {                                            \
    float a0, a1, a2, a3, b0, b1, b2, b3;                                  \
    LOADROW(r0 - 4 + (K), a0, a1, a2, a3, b0, b1, b2, b3);                 \
    float o0 = 0.f, o1 = 0.f, o2 = 0.f, o3 = 0.f;                          \
    float p0 = 0.f, p1 = 0.f, p2 = 0.f, p3 = 0.f;                          \
    if (SUB) LOADROW(r0 - 13 + (K), o0, o1, o2, o3, p0, p1, p2, p3);       \
    VUPD(0, a0, b0, o0, p0);                                               \
    VUPD(1, a1, b1, o1, p1);                                               \
    VUPD(2, a2, b2, o2, p2);                                               \
    VUPD(3, a3, b3, o3, p3);                                               \
    if (EMIT) {                                                            \
        *(float4*)&Vbuf[0][4 + c0] = make_float4(VI0,  VI1,  VI2,  VI3);   \
        *(float4*)&Vbuf[1][4 + c0] = make_float4(VJ0,  VJ1,  VJ2,  VJ3);   \
        *(float4*)&Vbuf[2][4 + c0] = make_float4(VII0, VII1, VII2, VII3);  \
        *(float4*)&Vbuf[3][4 + c0] = make_float4(VJJ0, VJJ1, VJJ2, VJJ3);  \
        *(float4*)&Vbuf[4][4 + c0] = make_float4(VIJ0, VIJ1, VIJ2, VIJ3);  \
        __syncthreads();                                                   \
        float HI0, HI1, HI2, HI3, HJ0, HJ1, HJ2, HJ3;                      \
        float HA0, HA1, HA2, HA3, HB0, HB1, HB2, HB3;                      \
        float HC0, HC1, HC2, HC3;                                          \
        HSUM(0, HI0, HI1, HI2, HI3);                                       \
        HSUM(1, HJ0, HJ1, HJ2, HJ3);                                       \
        HSUM(2, HA0, HA1, HA2, HA3);                                       \
        HSUM(3, HB0, HB1, HB2, HB3);                                       \
        HSUM(4, HC0, HC1, HC2, HC3);                                       \
        CC1(HI0, HJ0, HA0, HB0, HC0);                                      \
        CC1(HI1, HJ1, HA1, HB1, HC1);                                      \
        CC1(HI2, HJ2, HA2, HB2, HC2);                                      \
        CC1(HI3, HJ3, HA3, HB3, HC3);                                      \
        __syncthreads();                                                   \
    }                                                                      \
} while (0)

__global__ __launch_bounds__(128, 4) void ncc_main(const float* __restrict__ I,
                                                   const float* __restrict__ J,
                                                   float* __restrict__ partial) {
    const int u  = threadIdx.x;          // 0..127
    const int s  = blockIdx.x;           // strip (0..63)
    const int b  = blockIdx.y;           // image
    const int r0 = s * SH;
    const int c0 = 4 * u;                // first owned column
    const float inv81 = 1.0f / 81.0f;

    const float* Ib = I + (size_t)b * IMH * IMW;
    const float* Jb = J + (size_t)b * IMH * IMW;

    __shared__ float Vbuf[5][VROW];
    // zero the 8 pad cols (idx 0..3 and 516..519) of each of the 5 rows
    if (u < 40) {
        const int q = u >> 3, p = u & 7;
        Vbuf[q][p < 4 ? p : 512 + p] = 0.f;
    }
    __syncthreads();

    float VI0 = 0.f, VI1 = 0.f, VI2 = 0.f, VI3 = 0.f;
    float VJ0 = 0.f, VJ1 = 0.f, VJ2 = 0.f, VJ3 = 0.f;
    float VII0 = 0.f, VII1 = 0.f, VII2 = 0.f, VII3 = 0.f;
    float VJJ0 = 0.f, VJJ1 = 0.f, VJJ2 = 0.f, VJJ3 = 0.f;
    float VIJ0 = 0.f, VIJ1 = 0.f, VIJ2 = 0.f, VIJ3 = 0.f;
    float acc = 0.f;

    // 16 input rows: 8 warm-up (build V), 8 emit rows r0..r0+7.
    STEP( 0, 0, 0);
    STEP( 1, 0, 0);
    STEP( 2, 0, 0);
    STEP( 3, 0, 0);
    STEP( 4, 0, 0);
    STEP( 5, 0, 0);
    STEP( 6, 0, 0);
    STEP( 7, 0, 0);
    STEP( 8, 0, 1);
    STEP( 9, 1, 1);
    STEP(10, 1, 1);
    STEP(11, 1, 1);
    STEP(12, 1, 1);
    STEP(13, 1, 1);
    STEP(14, 1, 1);
    STEP(15, 1, 1);

    // block reduction: wave shuffle, then LDS across the 2 waves
    float sum = acc;
#pragma unroll
    for (int off = 32; off > 0; off >>= 1) sum += __shfl_down(sum, off, 64);

    __shared__ float wsum[2];
    if ((u & 63) == 0) wsum[u >> 6] = sum;
    __syncthreads();
    if (u == 0) {
        partial[(size_t)b * NSTRIP + s] = wsum[0] + wsum[1];
    }
}

__global__ __launch_bounds__(256) void ncc_reduce(const float* __restrict__ partial,
                                                  float* __restrict__ out) {
    const int t = threadIdx.x;
    double ssum = 0.0;
    for (int idx = t; idx < NPART; idx += 256) ssum += (double)partial[idx];
#pragma unroll
    for (int off = 32; off > 0; off >>= 1) ssum += __shfl_down(ssum, off, 64);

    __shared__ double wsum[4];
    if ((t & 63) == 0) wsum[t >> 6] = ssum;
    __syncthreads();
    if (t == 0) {
        const double total = wsum[0] + wsum[1] + wsum[2] + wsum[3];
        out[0] = (float)(-total / 8388608.0);  // -mean over 32*512*512
    }
}

extern "C" void kernel_launch(void* const* d_in, const int* in_sizes, int n_in,
                              void* d_out, int out_size, void* d_ws, size_t ws_size,
                              hipStream_t stream) {
    const float* I = (const float*)d_in[0];  // y_true
    const float* J = (const float*)d_in[1];  // y_pred
    float* partial = (float*)d_ws;           // NPART floats
    float* out     = (float*)d_out;

    dim3 grid(NSTRIP, BATCH);
    ncc_main<<<grid, 128, 0, stream>>>(I, J, partial);
    ncc_reduce<<<1, 256, 0, stream>>>(partial, out);
}

// Round 7
// 118.448 us; speedup vs baseline: 1.5248x; 1.5248x over previous
//
#include <hip/hip_runtime.h>

// NCC2D fused: 5 box-sums (9x9, zero-pad) + cc + global mean.
// R7: R6 skeleton, but the outgoing-row SUBTRACT no longer re-reads global
// (R6 counters: FETCH 210MB = 2.875x input redundancy, kernel BW-bound at
// 3.3TB/s -> 107us). Incoming rows are kept in a 9-slot LDS ring (each
// thread reads/writes ONLY its own float4 -> no barriers for the ring).
// Each input row is read from global exactly once; SH=16 amortizes the
// vertical halo to 1.5x (~100MB).
//   * 256 threads x 2 cols (float2, 8B/lane coalesced), full 512-col width.
//   * V running sums in 10 named scalars; next-row prefetch pipelined.
//   * Horizontal 9-sums via Vbuf LDS exchange (2 barriers per emitted row).
//   * LDS 47.3KB -> 3 blocks/CU = 12 waves/CU resident (grid 32x32=1024).
// d_ws: 1024 block partials (float). Kernel 2 reduces in double -> -mean.

#define BATCH   32
#define IMH     512
#define IMW     512
#define SH      16           // output rows per block
#define NSTRIP  32           // 512/16, exact
#define NPART   (BATCH * NSTRIP)   // 1024
#define VROW    520          // 4 left pad + 512 + 4 right pad
#define NK      (SH + 8)     // input rows per block (24)

// horizontal 9-window sums (cols c-4..c+4) for the 2 owned cols from Vbuf
// row QI; window floats live at idx c0..c0+9 (idx = col + 4).
#define HWIN(QI, HA, HB) do {                                              \
    const float2 w0_ = *(const float2*)&Vbuf[QI][c0];                      \
    const float2 w1_ = *(const float2*)&Vbuf[QI][c0 + 2];                  \
    const float2 w2_ = *(const float2*)&Vbuf[QI][c0 + 4];                  \
    const float2 w3_ = *(const float2*)&Vbuf[QI][c0 + 6];                  \
    const float2 w4_ = *(const float2*)&Vbuf[QI][c0 + 8];                  \
    HA = ((w0_.x + w0_.y) + (w1_.x + w1_.y))                               \
       + ((w2_.x + w2_.y) + (w3_.x + w3_.y)) + w4_.x;                      \
    HB = HA + w4_.y - w0_.x;                                               \
} while (0)

#define CC1(AI, AJ, S2, S3, S4) do {                                       \
    const float cross = (S4) - (AI)*(AJ)*inv81;                            \
    const float ivv   = (S2) - (AI)*(AI)*inv81;                            \
    const float jvv   = (S3) - (AJ)*(AJ)*inv81;                            \
    acc += cross * cross * __builtin_amdgcn_rcpf(ivv * jvv + 1e-5f);       \
} while (0)

__global__ __launch_bounds__(256, 4) void ncc_main(const float* __restrict__ I,
                                                   const float* __restrict__ J,
                                                   float* __restrict__ partial) {
    const int u  = threadIdx.x;          // 0..255
    const int s  = blockIdx.x;           // strip (0..31)
    const int b  = blockIdx.y;           // image
    const int r0 = s * SH;
    const int c0 = 2 * u;                // first owned column
    const float inv81 = 1.0f / 81.0f;

    const float* Ib = I + (size_t)b * IMH * IMW;
    const float* Jb = J + (size_t)b * IMH * IMW;

    __shared__ float  Vbuf[5][VROW];     // 10.4 KB exchange buffer
    __shared__ float4 ring[9][256];      // 36.9 KB: 9-row history (I0,I1,J0,J1)

    // zero the 8 pad cols (idx 0..3, 516..519) of each of the 5 Vbuf rows
    if (u < 40) {
        const int q = u >> 3, p = u & 7;
        Vbuf[q][p < 4 ? p : 512 + p] = 0.f;
    }
    __syncthreads();

    float VI0 = 0.f, VI1 = 0.f, VJ0 = 0.f, VJ1 = 0.f;
    float VII0 = 0.f, VII1 = 0.f, VJJ0 = 0.f, VJJ1 = 0.f;
    float VIJ0 = 0.f, VIJ1 = 0.f;
    float acc = 0.f;
    int slot = 0;

    // prefetch row K=0 (row r0-4; OOB -> zeros)
    float2 ai = make_float2(0.f, 0.f), aj = make_float2(0.f, 0.f);
    {
        const int ri = r0 - 4;
        if ((unsigned)ri < (unsigned)IMH) {
            ai = *(const float2*)(Ib + (size_t)ri * IMW + c0);
            aj = *(const float2*)(Jb + (size_t)ri * IMW + c0);
        }
    }

#pragma unroll 1
    for (int K = 0; K < NK; ++K) {
        // software-pipelined prefetch of row K+1
        float2 nai = make_float2(0.f, 0.f), naj = make_float2(0.f, 0.f);
        {
            const int rin = r0 - 3 + K;
            if (K + 1 < NK && (unsigned)rin < (unsigned)IMH) {
                nai = *(const float2*)(Ib + (size_t)rin * IMW + c0);
                naj = *(const float2*)(Jb + (size_t)rin * IMW + c0);
            }
        }

        // ring: read outgoing row (K-9) then overwrite with incoming row K.
        // Same thread, same address -> program order suffices, no barrier.
        float4 oldv = make_float4(0.f, 0.f, 0.f, 0.f);
        if (K >= 9) oldv = ring[slot][u];
        ring[slot][u] = make_float4(ai.x, ai.y, aj.x, aj.y);
        slot = (slot == 8) ? 0 : slot + 1;

        // vertical running 9-row sums, 5 quantities x 2 cols
        VI0  += ai.x - oldv.x;             VI1  += ai.y - oldv.y;
        VJ0  += aj.x - oldv.z;             VJ1  += aj.y - oldv.w;
        VII0 += ai.x*ai.x - oldv.x*oldv.x; VII1 += ai.y*ai.y - oldv.y*oldv.y;
        VJJ0 += aj.x*aj.x - oldv.z*oldv.z; VJJ1 += aj.y*aj.y - oldv.w*oldv.w;
        VIJ0 += ai.x*aj.x - oldv.x*oldv.z; VIJ1 += ai.y*aj.y - oldv.y*oldv.w;

        if (K >= 8) {       // emit output row r0 + K - 8 (always in-image)
            *(float2*)&Vbuf[0][4 + c0] = make_float2(VI0,  VI1);
            *(float2*)&Vbuf[1][4 + c0] = make_float2(VJ0,  VJ1);
            *(float2*)&Vbuf[2][4 + c0] = make_float2(VII0, VII1);
            *(float2*)&Vbuf[3][4 + c0] = make_float2(VJJ0, VJJ1);
            *(float2*)&Vbuf[4][4 + c0] = make_float2(VIJ0, VIJ1);
            __syncthreads();
            float HI0, HI1, HJ0, HJ1, HA0, HA1, HB0, HB1, HC0, HC1;
            HWIN(0, HI0, HI1);
            HWIN(1, HJ0, HJ1);
            HWIN(2, HA0, HA1);
            HWIN(3, HB0, HB1);
            HWIN(4, HC0, HC1);
            CC1(HI0, HJ0, HA0, HB0, HC0);
            CC1(HI1, HJ1, HA1, HB1, HC1);
            __syncthreads();   // WAR: next emit's Vbuf writes vs these reads
        }

        ai = nai; aj = naj;
    }

    // block reduction: wave shuffle, then LDS across the 4 waves
    float sum = acc;
#pragma unroll
    for (int off = 32; off > 0; off >>= 1) sum += __shfl_down(sum, off, 64);

    __shared__ float wsum[4];
    if ((u & 63) == 0) wsum[u >> 6] = sum;
    __syncthreads();
    if (u == 0) {
        partial[(size_t)b * NSTRIP + s] = wsum[0] + wsum[1] + wsum[2] + wsum[3];
    }
}

__global__ __launch_bounds__(256) void ncc_reduce(const float* __restrict__ partial,
                                                  float* __restrict__ out) {
    const int t = threadIdx.x;
    double ssum = 0.0;
    for (int idx = t; idx < NPART; idx += 256) ssum += (double)partial[idx];
#pragma unroll
    for (int off = 32; off > 0; off >>= 1) ssum += __shfl_down(ssum, off, 64);

    __shared__ double wsum[4];
    if ((t & 63) == 0) wsum[t >> 6] = ssum;
    __syncthreads();
    if (t == 0) {
        const double total = wsum[0] + wsum[1] + wsum[2] + wsum[3];
        out[0] = (float)(-total / 8388608.0);  // -mean over 32*512*512
    }
}

extern "C" void kernel_launch(void* const* d_in, const int* in_sizes, int n_in,
                              void* d_out, int out_size, void* d_ws, size_t ws_size,
                              hipStream_t stream) {
    const float* I = (const float*)d_in[0];  // y_true
    const float* J = (const float*)d_in[1];  // y_pred
    float* partial = (float*)d_ws;           // NPART floats
    float* out     = (float*)d_out;

    dim3 grid(NSTRIP, BATCH);
    ncc_main<<<grid, 256, 0, stream>>>(I, J, partial);
    ncc_reduce<<<1, 256, 0, stream>>>(partial, out);
}